// Round 2
// baseline (2320.282 us; speedup 1.0000x reference)
//
#include <hip/hip_runtime.h>

#define NN 500
#define BB 8
#define FIN 8
#define TT 12
#define HH 16
#define EE 8000
#define HG 4000          // N*HID
#define IG 8000          // N*H3
#define G3 12000         // 3*HG
#define MM 96            // T*B

// ---------------------------------------------------------------- graph prep
__global__ __launch_bounds__(512) void k_prep(const int* __restrict__ src,
                                              const int* __restrict__ dst,
                                              float* __restrict__ n_out,
                                              float* __restrict__ n_in,
                                              int* __restrict__ row_ptr,
                                              int* __restrict__ edge_src) {
  __shared__ int s_dout[NN];
  __shared__ int s_din[NN];
  __shared__ int s_off[NN + 1];
  int tid = threadIdx.x;
  for (int i = tid; i < NN; i += 512) { s_dout[i] = 0; s_din[i] = 0; }
  __syncthreads();
  for (int e = tid; e < EE; e += 512) {
    atomicAdd(&s_dout[src[e]], 1);
    atomicAdd(&s_din[dst[e]], 1);
  }
  __syncthreads();
  if (tid == 0) {
    int acc = 0;
    for (int n = 0; n < NN; ++n) { s_off[n] = acc; acc += s_din[n]; }
    s_off[NN] = acc;
  }
  __syncthreads();
  for (int i = tid; i < NN; i += 512) {
    int dv = s_dout[i]; if (dv < 1) dv = 1;
    int iv = s_din[i];  if (iv < 1) iv = 1;
    n_out[i] = rsqrtf((float)dv);
    n_in[i]  = rsqrtf((float)iv);
    row_ptr[i] = s_off[i];
  }
  if (tid == 0) row_ptr[NN] = s_off[NN];
  __syncthreads();
  for (int e = tid; e < EE; e += 512) {
    int d = dst[e];
    int pos = atomicAdd(&s_off[d], 1);
    edge_src[pos] = src[e];
  }
}

// ------------------------------------------------- transpose inputs to [t][n][b][f]
__global__ __launch_bounds__(256) void k_transpose(const float* __restrict__ in,
                                                   float* __restrict__ out) {
  int idx = blockIdx.x * 256 + threadIdx.x;   // over T*N*B*FIN
  if (idx >= TT * NN * BB * FIN) return;
  int f = idx % FIN;
  int b = (idx / FIN) % BB;
  int n = (idx / (FIN * BB)) % NN;
  int t = idx / (FIN * BB * NN);
  out[idx] = in[((n * BB + b) * FIN + f) * TT + t];
}

// ---------------------------------------------------------------- GCN layer
// x: [T][N][B][FI]  ->  y: [T][N][B][FO]  (or OUT_SEQ: [T][B][N][FO])
template <int FI, int FO, bool RELU, bool OUT_SEQ>
__global__ __launch_bounds__(128) void k_gcn(const float* __restrict__ x,
                                             const float* __restrict__ W,
                                             const float* __restrict__ bias,
                                             const float* __restrict__ n_out,
                                             const float* __restrict__ n_in,
                                             const int* __restrict__ row_ptr,
                                             const int* __restrict__ edge_src,
                                             float* __restrict__ y) {
  int bid = blockIdx.x;             // t*NN + n
  int t = bid / NN, n = bid % NN;
  __shared__ float sW[FI * FO];
  __shared__ float sB[FO];
  __shared__ float sAgg[BB * FI];
  int tid = threadIdx.x;
  for (int i = tid; i < FI * FO; i += 128) sW[i] = W[i];   // FI*FO can exceed 128!
  if (tid < FO) sB[tid] = bias[tid];
  int r0 = row_ptr[n], r1 = row_ptr[n + 1];
  if (tid < BB * FI) {
    int b = tid / FI, fi = tid % FI;
    float acc = 0.f;
    for (int p = r0; p < r1; ++p) {
      int s = edge_src[p];
      acc += x[((t * NN + s) * BB + b) * FI + fi] * n_out[s];
    }
    sAgg[tid] = acc * n_in[n];
  }
  __syncthreads();
  if (tid < BB * FO) {
    int b = tid / FO, fo = tid % FO;
    float v = sB[fo];
#pragma unroll
    for (int fi = 0; fi < FI; ++fi) v += sAgg[b * FI + fi] * sW[fi * FO + fo];
    if (RELU) v = fmaxf(v, 0.f);
    int oidx = OUT_SEQ ? (((t * BB + b) * NN + n) * FO + fo)
                       : (((t * NN + n) * BB + b) * FO + fo);
    y[oidx] = v;
  }
}

// ------------------------------------------------------------ gi = X @ Wih^T
// X: [96][8000], Wih: [12000][8000].  gip: [2][96][12000] K-split partials.
// grid (250, 2), block 256.  JT=48 j per block, KC=40 k per LDS tile.
#define KC 40
#define JT 48
__global__ __launch_bounds__(256) void k_gemm_gi(const float* __restrict__ X,
                                                 const float* __restrict__ Wih,
                                                 float* __restrict__ gip) {
  int j0 = blockIdx.x * JT;
  int ks = blockIdx.y;
  int kbase = ks * 4000;
  __shared__ float sX[MM * 44];    // padded stride 44
  __shared__ float sW[JT * 44];
  int tid = threadIdx.x;
  int jg = tid & 15;               // 0..15, owns j = j0 + jg + r*16, r=0..2
  int mg = tid >> 4;               // 0..15, owns m = mg*6 + i, i=0..5
  float acc[3][6] = {};
  for (int it = 0; it < 100; ++it) {
    int k0 = kbase + it * KC;
    __syncthreads();
#pragma unroll
    for (int l = 0; l < 15; ++l) {               // 96*40/256 = 15
      int idx = l * 256 + tid;
      int r = idx / KC, kk = idx % KC;
      sX[r * 44 + kk] = X[r * IG + k0 + kk];
    }
#pragma unroll
    for (int l = 0; l < 8; ++l) {                // 48*40 = 1920
      int idx = l * 256 + tid;
      if (idx < JT * KC) {
        int r = idx / KC, kk = idx % KC;
        sW[r * 44 + kk] = Wih[(j0 + r) * IG + k0 + kk];
      }
    }
    __syncthreads();
#pragma unroll
    for (int k4 = 0; k4 < KC / 4; ++k4) {
      float4 w[3], xv[6];
#pragma unroll
      for (int r = 0; r < 3; ++r)
        w[r] = *(const float4*)&sW[(jg + r * 16) * 44 + k4 * 4];
#pragma unroll
      for (int i = 0; i < 6; ++i)
        xv[i] = *(const float4*)&sX[(mg * 6 + i) * 44 + k4 * 4];
#pragma unroll
      for (int r = 0; r < 3; ++r)
#pragma unroll
        for (int i = 0; i < 6; ++i)
          acc[r][i] += w[r].x * xv[i].x + w[r].y * xv[i].y +
                       w[r].z * xv[i].z + w[r].w * xv[i].w;
    }
  }
  float* out = gip + (size_t)ks * (MM * G3);
#pragma unroll
  for (int r = 0; r < 3; ++r) {
    int j = j0 + jg + r * 16;
#pragma unroll
    for (int i = 0; i < 6; ++i) {
      int m = mg * 6 + i;
      out[m * G3 + j] = acc[r][i];
    }
  }
}

// ------------------------------------------------------------ gh = h @ Whh^T
// ht: [4000][8] (k-major), Whh: [12000][4000], ghp: [4][8][12000] partials.
// grid (375, 4), block 256.  32 j per block, 1000 k per k-slice.
__device__ __forceinline__ int swz(int f) { return f ^ (((f >> 3) & 3) << 1); }

__global__ __launch_bounds__(256) void k_gemm_gh(const float* __restrict__ ht,
                                                 const float* __restrict__ Whh,
                                                 float* __restrict__ ghp) {
  int j0 = blockIdx.x * 32;
  int ks = blockIdx.y;             // 0..3
  int kbase = ks * 1000;
  __shared__ float4 sH4[2000];     // [1000 k][8 m] as float4 pairs, swizzled
  int tid = threadIdx.x;
  const float4* H4 = (const float4*)ht;
#pragma unroll
  for (int l = 0; l < 8; ++l) {
    int fidx = l * 256 + tid;
    if (fidx < 2000) sH4[swz(fidx)] = H4[kbase * 2 + fidx];
  }
  __syncthreads();
  int jl = tid >> 3;               // 0..31
  int k8 = tid & 7;                // 0..7
  const float4* W4 = (const float4*)Whh;
  const float4* Wrow = W4 + (size_t)(j0 + jl) * 1000 + kbase / 4;
  float acc[8] = {};
#pragma unroll
  for (int i = 0; i < 32; ++i) {
    int kq = i * 8 + k8;           // float4 index within slice, 0..249
    if (kq < 250) {
      float4 w4 = Wrow[kq];
#pragma unroll
      for (int kk = 0; kk < 4; ++kk) {
        int f0 = kq * 8 + 2 * kk;
        float4 ha = sH4[swz(f0)];
        float4 hb = sH4[swz(f0 + 1)];
        float wv = (kk == 0) ? w4.x : (kk == 1) ? w4.y : (kk == 2) ? w4.z : w4.w;
        acc[0] += ha.x * wv; acc[1] += ha.y * wv;
        acc[2] += ha.z * wv; acc[3] += ha.w * wv;
        acc[4] += hb.x * wv; acc[5] += hb.y * wv;
        acc[6] += hb.z * wv; acc[7] += hb.w * wv;
      }
    }
  }
  // 8-lane shuffle reduce over k8
#pragma unroll
  for (int m = 0; m < 8; ++m) {
    float v = acc[m];
    v += __shfl_down(v, 4, 8);
    v += __shfl_down(v, 2, 8);
    v += __shfl_down(v, 1, 8);
    acc[m] = v;
  }
  if (k8 == 0) {
    float* out = ghp + (size_t)ks * (BB * G3);
#pragma unroll
    for (int m = 0; m < 8; ++m) out[m * G3 + j0 + jl] = acc[m];
  }
}

// ---------------------------------------------------------------- gates
__global__ __launch_bounds__(256) void k_gates(const float* __restrict__ gip,
                                               const float* __restrict__ ghp,
                                               const float* __restrict__ b_ih,
                                               const float* __restrict__ b_hh,
                                               const float* __restrict__ ht_old,
                                               float* __restrict__ ht_new,
                                               float* __restrict__ hout, int t) {
  int idx = blockIdx.x * 256 + threadIdx.x;
  if (idx >= BB * HG) return;
  int b = idx / HG, q = idx % HG;
  int m = t * BB + b;
  const float* g0 = gip;
  const float* g1 = gip + (size_t)MM * G3;
  float ir = b_ih[q]          + g0[m * G3 + q]          + g1[m * G3 + q];
  float iz = b_ih[q + HG]     + g0[m * G3 + q + HG]     + g1[m * G3 + q + HG];
  float in_ = b_ih[q + 2*HG]  + g0[m * G3 + q + 2*HG]   + g1[m * G3 + q + 2*HG];
  float hr = b_hh[q], hz = b_hh[q + HG], hn = b_hh[q + 2*HG];
#pragma unroll
  for (int s = 0; s < 4; ++s) {
    const float* gh = ghp + (size_t)s * (BB * G3) + b * G3;
    hr += gh[q]; hz += gh[q + HG]; hn += gh[q + 2*HG];
  }
  float r = 1.f / (1.f + __expf(-(ir + hr)));
  float z = 1.f / (1.f + __expf(-(iz + hz)));
  float nn = tanhf(in_ + r * hn);
  float ho = ht_old[q * BB + b];
  float h = (1.f - z) * nn + z * ho;
  ht_new[q * BB + b] = h;
  if (hout) hout[b * HG + q] = h;
}

// ---------------------------------------------------------------- launcher
extern "C" void kernel_launch(void* const* d_in, const int* in_sizes, int n_in,
                              void* d_out, int out_size, void* d_ws, size_t ws_size,
                              hipStream_t stream) {
  const float* x_in = (const float*)d_in[0];
  const int*   src  = (const int*)d_in[1];
  const int*   dst  = (const int*)d_in[2];
  const float* W1   = (const float*)d_in[3];
  const float* b1   = (const float*)d_in[4];
  const float* W2   = (const float*)d_in[5];
  const float* b2   = (const float*)d_in[6];
  const float* W3   = (const float*)d_in[7];
  const float* b3   = (const float*)d_in[8];
  const float* Wih  = (const float*)d_in[9];
  const float* Whh  = (const float*)d_in[10];
  const float* bih  = (const float*)d_in[11];
  const float* bhh  = (const float*)d_in[12];
  float* out = (float*)d_out;

  float* W = (float*)d_ws;
  size_t off = 0;
  float* n_out = W + off; off += 512;
  float* n_in_ = W + off; off += 512;
  float* x0    = W + off; off += (size_t)TT * NN * BB * FIN;   // 384000
  float* xa    = W + off; off += (size_t)TT * NN * BB * HH;    // 768000
  float* xb    = W + off; off += (size_t)TT * NN * BB * HH;    // 768000
  float* xseq  = W + off; off += (size_t)MM * IG;              // 768000
  float* gip   = W + off; off += (size_t)2 * MM * G3;          // 2304000
  float* ghp   = W + off; off += (size_t)4 * BB * G3;          // 384000
  float* ht0   = W + off; off += (size_t)HG * BB;              // 32000
  float* ht1   = W + off; off += (size_t)HG * BB;              // 32000
  int* row_ptr  = (int*)(W + off); off += 512;
  int* edge_src = (int*)(W + off); off += 8000;
  (void)ws_size; (void)in_sizes; (void)n_in; (void)out_size;

  hipMemsetAsync(ht0, 0, (size_t)HG * BB * sizeof(float), stream);
  k_prep<<<1, 512, 0, stream>>>(src, dst, n_out, n_in_, row_ptr, edge_src);
  k_transpose<<<(TT * NN * BB * FIN + 255) / 256, 256, 0, stream>>>(x_in, x0);
  k_gcn<FIN, HH, true, false><<<TT * NN, 128, 0, stream>>>(x0, W1, b1, n_out, n_in_, row_ptr, edge_src, xa);
  k_gcn<HH, HH, true, false><<<TT * NN, 128, 0, stream>>>(xa, W2, b2, n_out, n_in_, row_ptr, edge_src, xb);
  k_gcn<HH, HH, false, true><<<TT * NN, 128, 0, stream>>>(xb, W3, b3, n_out, n_in_, row_ptr, edge_src, xseq);
  k_gemm_gi<<<dim3(G3 / JT, 2), 256, 0, stream>>>(xseq, Wih, gip);

  float* hcur = ht0;
  float* hnxt = ht1;
  for (int t = 0; t < TT; ++t) {
    k_gemm_gh<<<dim3(G3 / 32, 4), 256, 0, stream>>>(hcur, Whh, ghp);
    k_gates<<<(BB * HG + 255) / 256, 256, 0, stream>>>(
        gip, ghp, bih, bhh, hcur, hnxt, (t == TT - 1) ? out : nullptr, t);
    float* tmp = hcur; hcur = hnxt; hnxt = tmp;
  }
}

// Round 3
// 784.888 us; speedup vs baseline: 2.9562x; 2.9562x over previous
//
#include <hip/hip_runtime.h>

#define NN 500
#define BB 8
#define FIN 8
#define TT 12
#define HH 16
#define EE 8000
#define HG 4000          // N*HID
#define IG 8000          // N*H3
#define G3 12000         // 3*HG
#define MM 96            // T*B

typedef __attribute__((ext_vector_type(8))) __bf16 bf16x8;
typedef __attribute__((ext_vector_type(4))) float f32x4;

// ---------------------------------------------------------------- graph prep
__global__ __launch_bounds__(512) void k_prep(const int* __restrict__ src,
                                              const int* __restrict__ dst,
                                              float* __restrict__ n_out,
                                              float* __restrict__ n_in,
                                              int* __restrict__ row_ptr,
                                              int* __restrict__ edge_src) {
  __shared__ int s_dout[NN];
  __shared__ int s_din[NN];
  __shared__ int s_off[NN + 1];
  int tid = threadIdx.x;
  for (int i = tid; i < NN; i += 512) { s_dout[i] = 0; s_din[i] = 0; }
  __syncthreads();
  for (int e = tid; e < EE; e += 512) {
    atomicAdd(&s_dout[src[e]], 1);
    atomicAdd(&s_din[dst[e]], 1);
  }
  __syncthreads();
  if (tid == 0) {
    int acc = 0;
    for (int n = 0; n < NN; ++n) { s_off[n] = acc; acc += s_din[n]; }
    s_off[NN] = acc;
  }
  __syncthreads();
  for (int i = tid; i < NN; i += 512) {
    int dv = s_dout[i]; if (dv < 1) dv = 1;
    int iv = s_din[i];  if (iv < 1) iv = 1;
    n_out[i] = rsqrtf((float)dv);
    n_in[i]  = rsqrtf((float)iv);
    row_ptr[i] = s_off[i];
  }
  if (tid == 0) row_ptr[NN] = s_off[NN];
  __syncthreads();
  for (int e = tid; e < EE; e += 512) {
    int d = dst[e];
    int pos = atomicAdd(&s_off[d], 1);
    edge_src[pos] = src[e];
  }
}

// ------------------------------------------------- transpose inputs to [t][n][b][f]
__global__ __launch_bounds__(256) void k_transpose(const float* __restrict__ in,
                                                   float* __restrict__ out) {
  int idx = blockIdx.x * 256 + threadIdx.x;   // over T*N*B*FIN
  if (idx >= TT * NN * BB * FIN) return;
  int f = idx % FIN;
  int b = (idx / FIN) % BB;
  int n = (idx / (FIN * BB)) % NN;
  int t = idx / (FIN * BB * NN);
  out[idx] = in[((n * BB + b) * FIN + f) * TT + t];
}

// ---------------------------------------------------------------- GCN layer
template <int FI, int FO, bool RELU, bool OUT_SEQ>
__global__ __launch_bounds__(128) void k_gcn(const float* __restrict__ x,
                                             const float* __restrict__ W,
                                             const float* __restrict__ bias,
                                             const float* __restrict__ n_out,
                                             const float* __restrict__ n_in,
                                             const int* __restrict__ row_ptr,
                                             const int* __restrict__ edge_src,
                                             float* __restrict__ y) {
  int bid = blockIdx.x;             // t*NN + n
  int t = bid / NN, n = bid % NN;
  __shared__ float sW[FI * FO];
  __shared__ float sB[FO];
  __shared__ float sAgg[BB * FI];
  int tid = threadIdx.x;
  for (int i = tid; i < FI * FO; i += 128) sW[i] = W[i];
  if (tid < FO) sB[tid] = bias[tid];
  int r0 = row_ptr[n], r1 = row_ptr[n + 1];
  if (tid < BB * FI) {
    int b = tid / FI, fi = tid % FI;
    float acc = 0.f;
    for (int p = r0; p < r1; ++p) {
      int s = edge_src[p];
      acc += x[((t * NN + s) * BB + b) * FI + fi] * n_out[s];
    }
    sAgg[tid] = acc * n_in[n];
  }
  __syncthreads();
  if (tid < BB * FO) {
    int b = tid / FO, fo = tid % FO;
    float v = sB[fo];
#pragma unroll
    for (int fi = 0; fi < FI; ++fi) v += sAgg[b * FI + fi] * sW[fi * FO + fo];
    if (RELU) v = fmaxf(v, 0.f);
    int oidx = OUT_SEQ ? (((t * BB + b) * NN + n) * FO + fo)
                       : (((t * NN + n) * BB + b) * FO + fo);
    y[oidx] = v;
  }
}

// ------------------------------------------------------------ gi = X @ Wih^T
// MFMA bf16x2-split (3 passes, fp32 acc).  X: [96][8000], Wih: [12000][8000].
// gip: [2][96][12000] K-split partials.  grid (375, 2), block 256 (4 waves).
// Block tile: 96m x 32j, K-chunk 32.  Wave: 3 m-tiles x 1 j-tile.
// LDS bf16 rows padded to 40 elems (80B stride -> 2-way conflicts only).
__device__ __forceinline__ ushort f2bf_rn(float v) {
  unsigned u = __float_as_uint(v);
  unsigned r = (u + 0x7FFFu + ((u >> 16) & 1u)) >> 16;
  return (ushort)r;
}
__device__ __forceinline__ float bf2f(ushort h) {
  return __uint_as_float(((unsigned)h) << 16);
}

__global__ __launch_bounds__(256, 4) void k_gemm_gi_mfma(const float* __restrict__ X,
                                                         const float* __restrict__ Wih,
                                                         float* __restrict__ gip) {
  __shared__ ushort sXhi[96 * 40];
  __shared__ ushort sXlo[96 * 40];
  __shared__ ushort sWhi[32 * 40];
  __shared__ ushort sWlo[32 * 40];
  int tid = threadIdx.x;
  int wave = tid >> 6, lane = tid & 63;
  int jb = blockIdx.x * 32;
  int kbase = blockIdx.y * 4000;         // K_s = 4000, 125 chunks of 32

  // staging assignment (fixed per thread)
  int xrow[3], xc4[3];
  const float4* px[3];
#pragma unroll
  for (int i = 0; i < 3; ++i) {
    int idx = i * 256 + tid;             // 768 float4 = 96 rows x 8 f4
    xrow[i] = idx >> 3; xc4[i] = idx & 7;
    px[i] = (const float4*)(X + (size_t)xrow[i] * IG + kbase + xc4[i] * 4);
  }
  int wrow = tid >> 3, wc4 = tid & 7;    // 256 f4 = 32 rows x 8 f4
  const float4* pw = (const float4*)(Wih + (size_t)(jb + wrow) * IG + kbase + wc4 * 4);

  // wave tile assignment
  int jt = wave & 1;                      // 0..1  (j-tile within block)
  int mh = wave >> 1;                     // 0..1  (m-half: 48 rows)
  f32x4 acc[3] = {{0.f,0.f,0.f,0.f},{0.f,0.f,0.f,0.f},{0.f,0.f,0.f,0.f}};

  float4 xr[3], wr;
#pragma unroll
  for (int i = 0; i < 3; ++i) xr[i] = px[i][0];
  wr = pw[0];

  int l15 = lane & 15;
  int colh = (lane >> 4) * 8;             // bf16 elem offset within padded row

  for (int c = 0; c < 125; ++c) {
    __syncthreads();                      // LDS free (prev reads done)
    // split & store X
#pragma unroll
    for (int i = 0; i < 3; ++i) {
      int base = xrow[i] * 40 + xc4[i] * 4;
      float v0 = xr[i].x, v1 = xr[i].y, v2 = xr[i].z, v3 = xr[i].w;
      ushort h0 = f2bf_rn(v0), h1 = f2bf_rn(v1), h2 = f2bf_rn(v2), h3 = f2bf_rn(v3);
      ushort l0 = f2bf_rn(v0 - bf2f(h0)), l1 = f2bf_rn(v1 - bf2f(h1));
      ushort l2 = f2bf_rn(v2 - bf2f(h2)), l3 = f2bf_rn(v3 - bf2f(h3));
      *(unsigned*)&sXhi[base]     = (unsigned)h0 | ((unsigned)h1 << 16);
      *(unsigned*)&sXhi[base + 2] = (unsigned)h2 | ((unsigned)h3 << 16);
      *(unsigned*)&sXlo[base]     = (unsigned)l0 | ((unsigned)l1 << 16);
      *(unsigned*)&sXlo[base + 2] = (unsigned)l2 | ((unsigned)l3 << 16);
    }
    {
      int base = wrow * 40 + wc4 * 4;
      float v0 = wr.x, v1 = wr.y, v2 = wr.z, v3 = wr.w;
      ushort h0 = f2bf_rn(v0), h1 = f2bf_rn(v1), h2 = f2bf_rn(v2), h3 = f2bf_rn(v3);
      ushort l0 = f2bf_rn(v0 - bf2f(h0)), l1 = f2bf_rn(v1 - bf2f(h1));
      ushort l2 = f2bf_rn(v2 - bf2f(h2)), l3 = f2bf_rn(v3 - bf2f(h3));
      *(unsigned*)&sWhi[base]     = (unsigned)h0 | ((unsigned)h1 << 16);
      *(unsigned*)&sWhi[base + 2] = (unsigned)h2 | ((unsigned)h3 << 16);
      *(unsigned*)&sWlo[base]     = (unsigned)l0 | ((unsigned)l1 << 16);
      *(unsigned*)&sWlo[base + 2] = (unsigned)l2 | ((unsigned)l3 << 16);
    }
    __syncthreads();                      // LDS ready
    if (c < 124) {                        // prefetch next chunk (overlaps MFMA)
#pragma unroll
      for (int i = 0; i < 3; ++i) xr[i] = px[i][(c + 1) * 8];
      wr = pw[(c + 1) * 8];
    }
    // fragments + MFMA
    bf16x8 bhi = *(const bf16x8*)&sWhi[(jt * 16 + l15) * 40 + colh];
    bf16x8 blo = *(const bf16x8*)&sWlo[(jt * 16 + l15) * 40 + colh];
#pragma unroll
    for (int t = 0; t < 3; ++t) {
      int row = mh * 48 + t * 16 + l15;
      bf16x8 ahi = *(const bf16x8*)&sXhi[row * 40 + colh];
      bf16x8 alo = *(const bf16x8*)&sXlo[row * 40 + colh];
      acc[t] = __builtin_amdgcn_mfma_f32_16x16x32_bf16(ahi, bhi, acc[t], 0, 0, 0);
      acc[t] = __builtin_amdgcn_mfma_f32_16x16x32_bf16(ahi, blo, acc[t], 0, 0, 0);
      acc[t] = __builtin_amdgcn_mfma_f32_16x16x32_bf16(alo, bhi, acc[t], 0, 0, 0);
    }
  }

  // store: D col = lane&15 (j), row m = (lane>>4)*4 + reg   [m89-verified]
  float* out = gip + (size_t)blockIdx.y * (MM * G3);
  int j = jb + jt * 16 + l15;
#pragma unroll
  for (int t = 0; t < 3; ++t) {
    int mb = mh * 48 + t * 16 + (lane >> 4) * 4;
#pragma unroll
    for (int r = 0; r < 4; ++r)
      out[(size_t)(mb + r) * G3 + j] = acc[t][r];
  }
}

// ------------------------------------------------------------ gh = h @ Whh^T
// ht: [4000][8] (k-major), Whh: [12000][4000], ghp: [4][8][12000] partials.
__device__ __forceinline__ int swz(int f) { return f ^ (((f >> 3) & 3) << 1); }

__global__ __launch_bounds__(256) void k_gemm_gh(const float* __restrict__ ht,
                                                 const float* __restrict__ Whh,
                                                 float* __restrict__ ghp) {
  int j0 = blockIdx.x * 32;
  int ks = blockIdx.y;             // 0..3
  int kbase = ks * 1000;
  __shared__ float4 sH4[2000];     // [1000 k][8 m] as float4 pairs, swizzled
  int tid = threadIdx.x;
  const float4* H4 = (const float4*)ht;
#pragma unroll
  for (int l = 0; l < 8; ++l) {
    int fidx = l * 256 + tid;
    if (fidx < 2000) sH4[swz(fidx)] = H4[kbase * 2 + fidx];
  }
  __syncthreads();
  int jl = tid >> 3;               // 0..31
  int k8 = tid & 7;                // 0..7
  const float4* W4 = (const float4*)Whh;
  const float4* Wrow = W4 + (size_t)(j0 + jl) * 1000 + kbase / 4;
  float acc[8] = {};
#pragma unroll
  for (int i = 0; i < 32; ++i) {
    int kq = i * 8 + k8;           // float4 index within slice, 0..249
    if (kq < 250) {
      float4 w4 = Wrow[kq];
#pragma unroll
      for (int kk = 0; kk < 4; ++kk) {
        int f0 = kq * 8 + 2 * kk;
        float4 ha = sH4[swz(f0)];
        float4 hb = sH4[swz(f0 + 1)];
        float wv = (kk == 0) ? w4.x : (kk == 1) ? w4.y : (kk == 2) ? w4.z : w4.w;
        acc[0] += ha.x * wv; acc[1] += ha.y * wv;
        acc[2] += ha.z * wv; acc[3] += ha.w * wv;
        acc[4] += hb.x * wv; acc[5] += hb.y * wv;
        acc[6] += hb.z * wv; acc[7] += hb.w * wv;
      }
    }
  }
#pragma unroll
  for (int m = 0; m < 8; ++m) {
    float v = acc[m];
    v += __shfl_down(v, 4, 8);
    v += __shfl_down(v, 2, 8);
    v += __shfl_down(v, 1, 8);
    acc[m] = v;
  }
  if (k8 == 0) {
    float* out = ghp + (size_t)ks * (BB * G3);
#pragma unroll
    for (int m = 0; m < 8; ++m) out[m * G3 + j0 + jl] = acc[m];
  }
}

// ---------------------------------------------------------------- gates
__global__ __launch_bounds__(256) void k_gates(const float* __restrict__ gip,
                                               const float* __restrict__ ghp,
                                               const float* __restrict__ b_ih,
                                               const float* __restrict__ b_hh,
                                               const float* __restrict__ ht_old,
                                               float* __restrict__ ht_new,
                                               float* __restrict__ hout, int t) {
  int idx = blockIdx.x * 256 + threadIdx.x;
  if (idx >= BB * HG) return;
  int b = idx / HG, q = idx % HG;
  int m = t * BB + b;
  const float* g0 = gip;
  const float* g1 = gip + (size_t)MM * G3;
  float ir = b_ih[q]          + g0[m * G3 + q]          + g1[m * G3 + q];
  float iz = b_ih[q + HG]     + g0[m * G3 + q + HG]     + g1[m * G3 + q + HG];
  float in_ = b_ih[q + 2*HG]  + g0[m * G3 + q + 2*HG]   + g1[m * G3 + q + 2*HG];
  float hr = b_hh[q], hz = b_hh[q + HG], hn = b_hh[q + 2*HG];
#pragma unroll
  for (int s = 0; s < 4; ++s) {
    const float* gh = ghp + (size_t)s * (BB * G3) + b * G3;
    hr += gh[q]; hz += gh[q + HG]; hn += gh[q + 2*HG];
  }
  float r = 1.f / (1.f + __expf(-(ir + hr)));
  float z = 1.f / (1.f + __expf(-(iz + hz)));
  float nn = tanhf(in_ + r * hn);
  float ho = ht_old[q * BB + b];
  float h = (1.f - z) * nn + z * ho;
  ht_new[q * BB + b] = h;
  if (hout) hout[b * HG + q] = h;
}

// ---------------------------------------------------------------- launcher
extern "C" void kernel_launch(void* const* d_in, const int* in_sizes, int n_in,
                              void* d_out, int out_size, void* d_ws, size_t ws_size,
                              hipStream_t stream) {
  const float* x_in = (const float*)d_in[0];
  const int*   src  = (const int*)d_in[1];
  const int*   dst  = (const int*)d_in[2];
  const float* W1   = (const float*)d_in[3];
  const float* b1   = (const float*)d_in[4];
  const float* W2   = (const float*)d_in[5];
  const float* b2   = (const float*)d_in[6];
  const float* W3   = (const float*)d_in[7];
  const float* b3   = (const float*)d_in[8];
  const float* Wih  = (const float*)d_in[9];
  const float* Whh  = (const float*)d_in[10];
  const float* bih  = (const float*)d_in[11];
  const float* bhh  = (const float*)d_in[12];
  float* out = (float*)d_out;

  float* W = (float*)d_ws;
  size_t off = 0;
  float* n_out = W + off; off += 512;
  float* n_in_ = W + off; off += 512;
  float* x0    = W + off; off += (size_t)TT * NN * BB * FIN;   // 384000
  float* xa    = W + off; off += (size_t)TT * NN * BB * HH;    // 768000
  float* xb    = W + off; off += (size_t)TT * NN * BB * HH;    // 768000
  float* xseq  = W + off; off += (size_t)MM * IG;              // 768000
  float* gip   = W + off; off += (size_t)2 * MM * G3;          // 2304000
  float* ghp   = W + off; off += (size_t)4 * BB * G3;          // 384000
  float* ht0   = W + off; off += (size_t)HG * BB;              // 32000
  float* ht1   = W + off; off += (size_t)HG * BB;              // 32000
  int* row_ptr  = (int*)(W + off); off += 512;
  int* edge_src = (int*)(W + off); off += 8000;
  (void)ws_size; (void)in_sizes; (void)n_in; (void)out_size;

  hipMemsetAsync(ht0, 0, (size_t)HG * BB * sizeof(float), stream);
  k_prep<<<1, 512, 0, stream>>>(src, dst, n_out, n_in_, row_ptr, edge_src);
  k_transpose<<<(TT * NN * BB * FIN + 255) / 256, 256, 0, stream>>>(x_in, x0);
  k_gcn<FIN, HH, true, false><<<TT * NN, 128, 0, stream>>>(x0, W1, b1, n_out, n_in_, row_ptr, edge_src, xa);
  k_gcn<HH, HH, true, false><<<TT * NN, 128, 0, stream>>>(xa, W2, b2, n_out, n_in_, row_ptr, edge_src, xb);
  k_gcn<HH, HH, false, true><<<TT * NN, 128, 0, stream>>>(xb, W3, b3, n_out, n_in_, row_ptr, edge_src, xseq);
  k_gemm_gi_mfma<<<dim3(375, 2), 256, 0, stream>>>(xseq, Wih, gip);

  float* hcur = ht0;
  float* hnxt = ht1;
  for (int t = 0; t < TT; ++t) {
    k_gemm_gh<<<dim3(G3 / 32, 4), 256, 0, stream>>>(hcur, Whh, ghp);
    k_gates<<<(BB * HG + 255) / 256, 256, 0, stream>>>(
        gip, ghp, bih, bhh, hcur, hnxt, (t == TT - 1) ? out : nullptr, t);
    float* tmp = hcur; hcur = hnxt; hnxt = tmp;
  }
}

// Round 4
// 552.702 us; speedup vs baseline: 4.1981x; 1.4201x over previous
//
#include <hip/hip_runtime.h>

#define NN 500
#define BB 8
#define FIN 8
#define TT 12
#define HH 16
#define EE 8000
#define HG 4000          // N*HID
#define IG 8000          // N*H3
#define G3 12000         // 3*HG
#define MM 96            // T*B

typedef __attribute__((ext_vector_type(8))) _Float16 half8;
typedef __attribute__((ext_vector_type(4))) _Float16 half4v;
typedef __attribute__((ext_vector_type(4))) float f32x4;

// ---------------------------------------------------------------- graph prep
__global__ __launch_bounds__(512) void k_prep(const int* __restrict__ src,
                                              const int* __restrict__ dst,
                                              float* __restrict__ n_out,
                                              float* __restrict__ n_in,
                                              int* __restrict__ row_ptr,
                                              int* __restrict__ edge_src) {
  __shared__ int s_dout[NN];
  __shared__ int s_din[NN];
  __shared__ int s_off[NN + 1];
  int tid = threadIdx.x;
  for (int i = tid; i < NN; i += 512) { s_dout[i] = 0; s_din[i] = 0; }
  __syncthreads();
  for (int e = tid; e < EE; e += 512) {
    atomicAdd(&s_dout[src[e]], 1);
    atomicAdd(&s_din[dst[e]], 1);
  }
  __syncthreads();
  if (tid == 0) {
    int acc = 0;
    for (int n = 0; n < NN; ++n) { s_off[n] = acc; acc += s_din[n]; }
    s_off[NN] = acc;
  }
  __syncthreads();
  for (int i = tid; i < NN; i += 512) {
    int dv = s_dout[i]; if (dv < 1) dv = 1;
    int iv = s_din[i];  if (iv < 1) iv = 1;
    n_out[i] = rsqrtf((float)dv);
    n_in[i]  = rsqrtf((float)iv);
    row_ptr[i] = s_off[i];
  }
  if (tid == 0) row_ptr[NN] = s_off[NN];
  __syncthreads();
  for (int e = tid; e < EE; e += 512) {
    int d = dst[e];
    int pos = atomicAdd(&s_off[d], 1);
    edge_src[pos] = src[e];
  }
}

// ------------------------------------------------- transpose inputs to [t][n][b][f]
__global__ __launch_bounds__(256) void k_transpose(const float* __restrict__ in,
                                                   float* __restrict__ out) {
  int idx = blockIdx.x * 256 + threadIdx.x;   // over T*N*B*FIN
  if (idx >= TT * NN * BB * FIN) return;
  int f = idx % FIN;
  int b = (idx / FIN) % BB;
  int n = (idx / (FIN * BB)) % NN;
  int t = idx / (FIN * BB * NN);
  out[idx] = in[((n * BB + b) * FIN + f) * TT + t];
}

// ---------------------------------------------------------------- GCN layer
template <int FI, int FO, bool RELU, typename OT, bool OUT_SEQ>
__global__ __launch_bounds__(128) void k_gcn(const float* __restrict__ x,
                                             const float* __restrict__ W,
                                             const float* __restrict__ bias,
                                             const float* __restrict__ n_out,
                                             const float* __restrict__ n_in,
                                             const int* __restrict__ row_ptr,
                                             const int* __restrict__ edge_src,
                                             OT* __restrict__ y) {
  int bid = blockIdx.x;             // t*NN + n
  int t = bid / NN, n = bid % NN;
  __shared__ float sW[FI * FO];
  __shared__ float sB[FO];
  __shared__ float sAgg[BB * FI];
  int tid = threadIdx.x;
  for (int i = tid; i < FI * FO; i += 128) sW[i] = W[i];
  if (tid < FO) sB[tid] = bias[tid];
  int r0 = row_ptr[n], r1 = row_ptr[n + 1];
  if (tid < BB * FI) {
    int b = tid / FI, fi = tid % FI;
    float acc = 0.f;
    for (int p = r0; p < r1; ++p) {
      int s = edge_src[p];
      acc += x[((t * NN + s) * BB + b) * FI + fi] * n_out[s];
    }
    sAgg[tid] = acc * n_in[n];
  }
  __syncthreads();
  if (tid < BB * FO) {
    int b = tid / FO, fo = tid % FO;
    float v = sB[fo];
#pragma unroll
    for (int fi = 0; fi < FI; ++fi) v += sAgg[b * FI + fi] * sW[fi * FO + fo];
    if (RELU) v = fmaxf(v, 0.f);
    int oidx = OUT_SEQ ? (((t * BB + b) * NN + n) * FO + fo)
                       : (((t * NN + n) * BB + b) * FO + fo);
    y[oidx] = (OT)v;
  }
}

// ------------------------------------------------- Whh fp32 -> fp16 (once)
__global__ __launch_bounds__(256) void k_cvt_whh(const float* __restrict__ w,
                                                 _Float16* __restrict__ wh) {
  size_t i8 = ((size_t)blockIdx.x * 256 + threadIdx.x) * 8;
  if (i8 >= (size_t)G3 * HG) return;
  float4 a = *(const float4*)(w + i8);
  float4 b = *(const float4*)(w + i8 + 4);
  half8 h;
  h[0] = (_Float16)a.x; h[1] = (_Float16)a.y; h[2] = (_Float16)a.z; h[3] = (_Float16)a.w;
  h[4] = (_Float16)b.x; h[5] = (_Float16)b.y; h[6] = (_Float16)b.z; h[7] = (_Float16)b.w;
  *(half8*)(wh + i8) = h;
}

// ------------------------------------------------------------ gi = X @ Wih^T
// fp16 MFMA single pass.  Xh: [96][8000] fp16, Wih: [12000][8000] fp32 (cvt in-kernel).
// gip: [2][96][12000] K-split partials.  grid (375, 2), block 256 (4 waves).
// Block tile: 96m x 32j, K-chunk 32.  Wave: 3 m-tiles x 1 j-tile.
__global__ __launch_bounds__(256, 3) void k_gemm_gi_mfma(const _Float16* __restrict__ Xh,
                                                         const float* __restrict__ Wih,
                                                         float* __restrict__ gip) {
  __shared__ _Float16 sXh[96 * 40];   // rows padded to 40 halves (80B stride)
  __shared__ _Float16 sWh[32 * 40];
  int tid = threadIdx.x;
  int wave = tid >> 6, lane = tid & 63;
  int jb = blockIdx.x * 32;
  int kbase = blockIdx.y * 4000;       // K_s = 4000, 125 chunks of 32

  // staging assignment: X fp16, 3x 8B (half4) per thread
  int xrow[3], xc4[3];
  const ushort4* px[3];
#pragma unroll
  for (int i = 0; i < 3; ++i) {
    int idx = i * 256 + tid;           // 768 units = 96 rows x 8 half4
    xrow[i] = idx >> 3; xc4[i] = idx & 7;
    px[i] = (const ushort4*)(Xh + (size_t)xrow[i] * IG + kbase + xc4[i] * 4);
  }
  // W fp32, 1x float4 per thread
  int wrow = tid >> 3, wc4 = tid & 7;  // 256 f4 = 32 rows x 8 f4
  const float4* pw = (const float4*)(Wih + (size_t)(jb + wrow) * IG + kbase + wc4 * 4);

  int jt = wave & 1;                    // j-tile within block
  int mh = wave >> 1;                   // m-half (48 rows)
  f32x4 acc[3] = {{0.f,0.f,0.f,0.f},{0.f,0.f,0.f,0.f},{0.f,0.f,0.f,0.f}};

  ushort4 xr[3]; float4 wr;
#pragma unroll
  for (int i = 0; i < 3; ++i) xr[i] = px[i][0];
  wr = pw[0];

  int l15 = lane & 15;
  int colh = (lane >> 4) * 8;

  for (int c = 0; c < 125; ++c) {
    __syncthreads();
#pragma unroll
    for (int i = 0; i < 3; ++i)
      *(ushort4*)&sXh[xrow[i] * 40 + xc4[i] * 4] = xr[i];
    {
      half4v h;
      h[0] = (_Float16)wr.x; h[1] = (_Float16)wr.y;
      h[2] = (_Float16)wr.z; h[3] = (_Float16)wr.w;
      *(half4v*)&sWh[wrow * 40 + wc4 * 4] = h;
    }
    __syncthreads();
    if (c < 124) {
#pragma unroll
      for (int i = 0; i < 3; ++i) xr[i] = px[i][(c + 1) * 8];
      wr = pw[(c + 1) * 8];
    }
    half8 bfrag = *(const half8*)&sWh[(jt * 16 + l15) * 40 + colh];
#pragma unroll
    for (int t = 0; t < 3; ++t) {
      half8 afrag = *(const half8*)&sXh[(mh * 48 + t * 16 + l15) * 40 + colh];
      acc[t] = __builtin_amdgcn_mfma_f32_16x16x32_f16(afrag, bfrag, acc[t], 0, 0, 0);
    }
  }

  // D: col = lane&15 (j), row m = (lane>>4)*4 + reg  [m89-verified, round-3 validated]
  float* out = gip + (size_t)blockIdx.y * (MM * G3);
  int j = jb + jt * 16 + l15;
#pragma unroll
  for (int t = 0; t < 3; ++t) {
    int mb = mh * 48 + t * 16 + (lane >> 4) * 4;
#pragma unroll
    for (int r = 0; r < 4; ++r)
      out[(size_t)(mb + r) * G3 + j] = acc[t][r];
  }
}

// ------------------------------------------------------------ gh = h @ Whh^T
// ht: [4000][8] fp32 k-major, Whh_h: [12000][4000] fp16, ghp: [4][8][12000].
// grid (125, 4), block 256.  96 j per block (3 rows/thread), 1000 k per slice.
__device__ __forceinline__ int swz2(int f) { return f ^ (((f >> 4) & 7) << 1); }

__global__ __launch_bounds__(256) void k_gemm_gh(const float* __restrict__ ht,
                                                 const _Float16* __restrict__ Whh_h,
                                                 float* __restrict__ ghp) {
  int j0 = blockIdx.x * 96;
  int ks = blockIdx.y;             // 0..3
  int kbase = ks * 1000;           // halves
  __shared__ float4 sH4[2000];     // [1000 k][8 m] as float4 pairs, swizzled
  int tid = threadIdx.x;
  const float4* H4 = (const float4*)ht;
#pragma unroll
  for (int l = 0; l < 8; ++l) {
    int f = l * 256 + tid;
    if (f < 2000) sH4[swz2(f)] = H4[kbase * 2 + f];
  }
  __syncthreads();
  int jl = tid >> 3;               // 0..31
  int k8 = tid & 7;                // 0..7
  const half8* W0 = (const half8*)(Whh_h + (size_t)(j0 + jl)      * HG + kbase);
  const half8* W1 = (const half8*)(Whh_h + (size_t)(j0 + jl + 32) * HG + kbase);
  const half8* W2 = (const half8*)(Whh_h + (size_t)(j0 + jl + 64) * HG + kbase);
  float acc[3][8] = {};
  for (int i = 0; i < 16; ++i) {
    int kq = i * 8 + k8;           // half8 index within slice, 0..124
    if (kq < 125) {
      half8 w0 = W0[kq], w1 = W1[kq], w2 = W2[kq];
#pragma unroll
      for (int kk = 0; kk < 8; ++kk) {
        int f = (kq * 8 + kk) * 2;
        float4 ha = sH4[swz2(f)];
        float4 hb = sH4[swz2(f + 1)];
        float hm[8] = {ha.x, ha.y, ha.z, ha.w, hb.x, hb.y, hb.z, hb.w};
        float v0 = (float)w0[kk], v1 = (float)w1[kk], v2 = (float)w2[kk];
#pragma unroll
        for (int m = 0; m < 8; ++m) {
          acc[0][m] += hm[m] * v0;
          acc[1][m] += hm[m] * v1;
          acc[2][m] += hm[m] * v2;
        }
      }
    }
  }
#pragma unroll
  for (int r = 0; r < 3; ++r)
#pragma unroll
    for (int m = 0; m < 8; ++m) {
      float v = acc[r][m];
      v += __shfl_down(v, 4, 8);
      v += __shfl_down(v, 2, 8);
      v += __shfl_down(v, 1, 8);
      acc[r][m] = v;
    }
  if (k8 == 0) {
    float* outp = ghp + (size_t)ks * (BB * G3);
#pragma unroll
    for (int r = 0; r < 3; ++r) {
      int j = j0 + jl + r * 32;
#pragma unroll
      for (int m = 0; m < 8; ++m) outp[m * G3 + j] = acc[r][m];
    }
  }
}

// ---------------------------------------------------------------- gates
__global__ __launch_bounds__(256) void k_gates(const float* __restrict__ gip,
                                               const float* __restrict__ ghp,
                                               const float* __restrict__ b_ih,
                                               const float* __restrict__ b_hh,
                                               const float* __restrict__ ht_old,
                                               float* __restrict__ ht_new,
                                               float* __restrict__ hout, int t) {
  int idx = blockIdx.x * 256 + threadIdx.x;
  if (idx >= BB * HG) return;
  int b = idx / HG, q = idx % HG;
  int m = t * BB + b;
  const float* g0 = gip;
  const float* g1 = gip + (size_t)MM * G3;
  float ir = b_ih[q]          + g0[m * G3 + q]          + g1[m * G3 + q];
  float iz = b_ih[q + HG]     + g0[m * G3 + q + HG]     + g1[m * G3 + q + HG];
  float in_ = b_ih[q + 2*HG]  + g0[m * G3 + q + 2*HG]   + g1[m * G3 + q + 2*HG];
  float hr = b_hh[q], hz = b_hh[q + HG], hn = b_hh[q + 2*HG];
#pragma unroll
  for (int s = 0; s < 4; ++s) {
    const float* gh = ghp + (size_t)s * (BB * G3) + b * G3;
    hr += gh[q]; hz += gh[q + HG]; hn += gh[q + 2*HG];
  }
  float r = 1.f / (1.f + __expf(-(ir + hr)));
  float z = 1.f / (1.f + __expf(-(iz + hz)));
  float nn = tanhf(in_ + r * hn);
  float ho = ht_old[q * BB + b];
  float h = (1.f - z) * nn + z * ho;
  ht_new[q * BB + b] = h;
  if (hout) hout[b * HG + q] = h;
}

// ---------------------------------------------------------------- launcher
extern "C" void kernel_launch(void* const* d_in, const int* in_sizes, int n_in,
                              void* d_out, int out_size, void* d_ws, size_t ws_size,
                              hipStream_t stream) {
  const float* x_in = (const float*)d_in[0];
  const int*   src  = (const int*)d_in[1];
  const int*   dst  = (const int*)d_in[2];
  const float* W1   = (const float*)d_in[3];
  const float* b1   = (const float*)d_in[4];
  const float* W2   = (const float*)d_in[5];
  const float* b2   = (const float*)d_in[6];
  const float* W3   = (const float*)d_in[7];
  const float* b3   = (const float*)d_in[8];
  const float* Wih  = (const float*)d_in[9];
  const float* Whh  = (const float*)d_in[10];
  const float* bih  = (const float*)d_in[11];
  const float* bhh  = (const float*)d_in[12];
  float* out = (float*)d_out;

  float* W = (float*)d_ws;
  size_t off = 0;
  float* n_out = W + off; off += 512;
  float* n_in_ = W + off; off += 512;
  float* x0    = W + off; off += (size_t)TT * NN * BB * FIN;   // 384000
  float* xa    = W + off; off += (size_t)TT * NN * BB * HH;    // 768000
  float* xb    = W + off; off += (size_t)TT * NN * BB * HH;    // 768000
  _Float16* xseq = (_Float16*)(W + off); off += (size_t)MM * IG / 2;  // fp16 [96][8000]
  float* gip   = W + off; off += (size_t)2 * MM * G3;          // 2304000
  float* ghp   = W + off; off += (size_t)4 * BB * G3;          // 384000
  float* ht0   = W + off; off += (size_t)HG * BB;              // 32000
  float* ht1   = W + off; off += (size_t)HG * BB;              // 32000
  int* row_ptr  = (int*)(W + off); off += 512;
  int* edge_src = (int*)(W + off); off += 8000;
  off = (off + 3) & ~(size_t)3;                                // 16B align
  _Float16* whh_h = (_Float16*)(W + off); off += (size_t)G3 * HG / 2;  // 96 MB
  (void)ws_size; (void)in_sizes; (void)n_in; (void)out_size;

  hipMemsetAsync(ht0, 0, (size_t)HG * BB * sizeof(float), stream);
  k_cvt_whh<<<((size_t)G3 * HG / 8 + 255) / 256, 256, 0, stream>>>(Whh, whh_h);
  k_prep<<<1, 512, 0, stream>>>(src, dst, n_out, n_in_, row_ptr, edge_src);
  k_transpose<<<(TT * NN * BB * FIN + 255) / 256, 256, 0, stream>>>(x_in, x0);
  k_gcn<FIN, HH, true, float, false><<<TT * NN, 128, 0, stream>>>(x0, W1, b1, n_out, n_in_, row_ptr, edge_src, xa);
  k_gcn<HH, HH, true, float, false><<<TT * NN, 128, 0, stream>>>(xa, W2, b2, n_out, n_in_, row_ptr, edge_src, xb);
  k_gcn<HH, HH, false, _Float16, true><<<TT * NN, 128, 0, stream>>>(xb, W3, b3, n_out, n_in_, row_ptr, edge_src, xseq);
  k_gemm_gi_mfma<<<dim3(375, 2), 256, 0, stream>>>(xseq, Wih, gip);

  float* hcur = ht0;
  float* hnxt = ht1;
  for (int t = 0; t < TT; ++t) {
    k_gemm_gh<<<dim3(125, 4), 256, 0, stream>>>(hcur, whh_h, ghp);
    k_gates<<<(BB * HG + 255) / 256, 256, 0, stream>>>(
        gip, ghp, bih, bhh, hcur, hnxt, (t == TT - 1) ? out : nullptr, t);
    float* tmp = hcur; hcur = hnxt; hnxt = tmp;
  }
}